// Round 5
// baseline (1220.424 us; speedup 1.0000x reference)
//
#include <hip/hip_runtime.h>
#include <hip/hip_bf16.h>

typedef __hip_bfloat16 bf16;
typedef float f32x4 __attribute__((ext_vector_type(4)));
typedef __bf16 bf16x8 __attribute__((ext_vector_type(8)));
typedef short s16x8 __attribute__((ext_vector_type(8)));
typedef short s16x2 __attribute__((ext_vector_type(2)));

#define HDIM 768
#define NHEAD 8
#define BMOL 128
#define NPG 49
#define EPG 144
#define NNODE (BMOL * NPG)     /* 6272 */
#define NEDGE (BMOL * EPG)     /* 18432 */
#define NH 6144                /* NHEAD*HDIM */
#define G3 2304                /* 3*HDIM */

__device__ __forceinline__ float b2f(short s) {
    unsigned int u = ((unsigned int)(unsigned short)s) << 16;
    return __builtin_bit_cast(float, u);
}

__device__ __forceinline__ void async16(const bf16* g, bf16* l) {
    __builtin_amdgcn_global_load_lds(
        (const __attribute__((address_space(1))) void*)g,
        (__attribute__((address_space(3))) void*)l, 16, 0, 0);
}

#define VMCNT(n) asm volatile("s_waitcnt vmcnt(" #n ")" ::: "memory")
#define SBAR()                                 \
    do {                                       \
        asm volatile("" ::: "memory");         \
        __builtin_amdgcn_s_barrier();          \
        asm volatile("" ::: "memory");         \
    } while (0)

// ---------------------------------------------------------------------------
// 256x256-tile 8-phase bf16 GEMM (HK-style schedule in plain HIP).
// C[M,N] = A[M,K] @ Bt[N,K]^T + bias[N], K = 768 (12 K-tiles of 64).
// 512 threads = 8 waves (2M x 4N), each wave owns a 128x64 output tile.
// LDS: 2 buffers x (A 256x64 + B 256x64) bf16 = 128 KiB.
// Bank swizzle: byte-in-row o (128B rows) stored at o ^ ((row&1)<<6)
// ^ ((row&2)<<4) -- conflict-free b128 fragment reads (8 lanes/16B slot),
// applied by pre-swizzling the global source column; ds_read XORs the same.
// vmcnt(4) at phases 4/8 (queue-trace verified: every buffer fully staged
// before first read; deeper counts leave A-h1 in flight -> race).
// A-chunk-resident XCD walk: per XCD, iterate (A-chunk of 5 m-tiles,
// 1.97 MB L2-fits) x (3 n-cols) x (5 m-tiles) so each A-chunk is fetched
// once and reused across the XCD's 3 B-columns.  Prior m-major walk swept
// all of A (9.6 MB > 4 MB L2) per n-column -> 230 MB chip FETCH.
// M-tail: last row-tile clamps A-row loads to NNODE-1, masks C stores.
// z selects (Bt,bias,C): 0->fs, 1->fd.
// ---------------------------------------------------------------------------
__global__ __launch_bounds__(512, 2) void gemm_bt8(
    const bf16* __restrict__ A, const bf16* __restrict__ Bt0,
    const bf16* __restrict__ Bt1, const float* __restrict__ bias0,
    const float* __restrict__ bias1, bf16* __restrict__ C0,
    bf16* __restrict__ C1) {
    __shared__ __align__(16) char smem[131072];
    bf16* lA = (bf16*)smem;                // [2 buf][2 half][8192]  64 KiB
    bf16* lB = (bf16*)(smem + 65536);      // same                  64 KiB

    const int tid = threadIdx.x;
    const int lane = tid & 63;
    const int wave = tid >> 6;
    const int l16 = lane & 15;
    const int quad = lane >> 4;
    const int wm = wave >> 2;  // 0..1
    const int wn = wave & 3;   // 0..3
    const int K = HDIM;

    // A-chunk-resident bijective XCD walk (600 tiles/plane, 600 % 8 == 0):
    // id -> (xcd, mc, ncol, moff); consecutive generations on one XCD hold
    // (mc,*) fixed across ncol sweeps -> A-chunk (5 tiles, 1.97 MB) L2-hits.
    int id = blockIdx.y * 24 + blockIdx.x;
    const int xcd = id & 7;
    const int loc = id >> 3;          // 0..74
    const int mc = loc / 15;          // 0..4  A-chunk
    const int rem = loc % 15;
    const int ncol = rem / 5;         // 0..2
    const int moff = rem % 5;         // 0..4
    const int m0 = (mc * 5 + moff) * 256;
    const int n0 = (xcd * 3 + ncol) * 256;

    const bf16* Bt = blockIdx.z ? Bt1 : Bt0;
    const float* bias = blockIdx.z ? bias1 : bias0;
    bf16* C = blockIdx.z ? C1 : C0;

    // ---- staging: thread's linear LDS chunk -> pre-swizzled global source
    const int srow = tid >> 3;  // 0..63 (row within 64-row chunk)
    const int ecol =
        ((tid & 7) * 8) ^ ((srow & 1) * 32) ^ ((srow & 2) * 8);
    // A row pointers per (half h, chunk c): row = m0+srow+h*128+c*64,
    // clamped to NNODE-1 (only the last row-tile clamps; masked at store).
    const bf16* gAr[4];
#pragma unroll
    for (int hc = 0; hc < 4; ++hc) {
        int r = m0 + srow + hc * 64;
        if (r > NNODE - 1) r = NNODE - 1;
        gAr[hc] = A + (size_t)r * K + ecol;
    }
    const bf16* gB = Bt + (size_t)(n0 + srow) * K + ecol;
    const size_t hstep = (size_t)128 * K;  // half-panel row step
    const size_t cstep = (size_t)64 * K;   // chunk row step
    bf16* dA = lA + tid * 8;  // + buf*16384 + h*8192 (elements)
    bf16* dB = lB + tid * 8;

#define STAGE_A(buf, h, kt)                                     \
    do {                                                        \
        bf16* _d = dA + (buf)*16384 + (h)*8192;                 \
        async16(gAr[(h)*2] + (size_t)(kt) * 64, _d);            \
        async16(gAr[(h)*2 + 1] + (size_t)(kt) * 64, _d + 4096); \
    } while (0)
#define STAGE_B(buf, h, kt)                                     \
    do {                                                        \
        const bf16* _s = gB + (h)*hstep + (size_t)(kt) * 64;    \
        bf16* _d = dB + (buf)*16384 + (h)*8192;                 \
        async16(_s, _d);                                        \
        async16(_s + cstep, _d + 4096);                         \
    } while (0)

    // ---- ds_read fragment addressing: row base + XOR-swizzled slot
    const int q16 = quad * 16;
    const int sw = ((l16 & 1) << 6) | ((l16 & 2) << 4);
    const char* laRow = (const char*)lA + wm * 16384 + l16 * 128;
    const char* lbRow =
        (const char*)lB + (wn >> 1) * 16384 + (wn & 1) * 8192 + l16 * 128;

#define LDA8(buf, f, ks) \
    (*(const bf16x8*)(laRow + (buf)*32768 + (f)*2048 + ((q16 + (ks)*64) ^ sw)))
#define LDB8(buf, j, ks) \
    (*(const bf16x8*)(lbRow + (buf)*32768 + (j)*2048 + ((q16 + (ks)*64) ^ sw)))

    f32x4 acc[8][4];
#pragma unroll
    for (int i = 0; i < 8; ++i)
#pragma unroll
        for (int j = 0; j < 4; ++j) acc[i][j] = (f32x4){0.f, 0.f, 0.f, 0.f};
    bf16x8 bfr[4][2];

#define MF(i, j, ks, areg)                                             \
    acc[i][j] = __builtin_amdgcn_mfma_f32_16x16x32_bf16(areg, bfr[j][ks], \
                                                        acc[i][j], 0, 0, 0)

#define PHASE(buf, q, LB, STG, WAIT)                                   \
    do {                                                               \
        bf16x8 a00 = LDA8(buf, (q)*2, 0);                              \
        bf16x8 a01 = LDA8(buf, (q)*2, 1);                              \
        bf16x8 a10 = LDA8(buf, (q)*2 + 1, 0);                          \
        bf16x8 a11 = LDA8(buf, (q)*2 + 1, 1);                          \
        if (LB) {                                                      \
            bfr[0][0] = LDB8(buf, 0, 0); bfr[0][1] = LDB8(buf, 0, 1);  \
            bfr[1][0] = LDB8(buf, 1, 0); bfr[1][1] = LDB8(buf, 1, 1);  \
            bfr[2][0] = LDB8(buf, 2, 0); bfr[2][1] = LDB8(buf, 2, 1);  \
            bfr[3][0] = LDB8(buf, 3, 0); bfr[3][1] = LDB8(buf, 3, 1);  \
        }                                                              \
        STG;                                                           \
        SBAR();                                                        \
        __builtin_amdgcn_s_setprio(1);                                 \
        MF((q)*2, 0, 0, a00); MF((q)*2, 1, 0, a00);                    \
        MF((q)*2, 2, 0, a00); MF((q)*2, 3, 0, a00);                    \
        MF((q)*2 + 1, 0, 0, a10); MF((q)*2 + 1, 1, 0, a10);            \
        MF((q)*2 + 1, 2, 0, a10); MF((q)*2 + 1, 3, 0, a10);            \
        MF((q)*2, 0, 1, a01); MF((q)*2, 1, 1, a01);                    \
        MF((q)*2, 2, 1, a01); MF((q)*2, 3, 1, a01);                    \
        MF((q)*2 + 1, 0, 1, a11); MF((q)*2 + 1, 1, 1, a11);            \
        MF((q)*2 + 1, 2, 1, a11); MF((q)*2 + 1, 3, 1, a11);            \
        __builtin_amdgcn_s_setprio(0);                                 \
        WAIT;                                                          \
        SBAR();                                                        \
    } while (0)

    // ---- prologue: A0,B0 (buf0) + B1 (buf1); leave B1's 4 loads in flight
    STAGE_A(0, 0, 0); STAGE_A(0, 1, 0);
    STAGE_B(0, 0, 0); STAGE_B(0, 1, 0);
    STAGE_B(1, 0, 1); STAGE_B(1, 1, 1);
    VMCNT(4);
    SBAR();

    // ---- main loop.  Queue trace (loads, oldest first), steady state:
    //  enter ph1: [B(t0+1) x4] -> ph1,2 +A(t0+1) -> ph3,4 +B(t0+2);
    //  ph4 VMCNT(4): drains B(t0+1),A(t0+1) (ph5 reads both) leaves B(t0+2);
    //  ph5,6 +A(t0+2), ph7,8 +B(t0+3); ph8 VMCNT(4): drains A/B(t0+2)
    //  (next ph1 reads them), leaves B(t0+3).  Sound.
    int t0 = 0;
    for (int it = 0; it < 5; ++it, t0 += 2) {
        PHASE(0, 0, 1, STAGE_A(1, 0, t0 + 1), );
        PHASE(0, 1, 0, STAGE_A(1, 1, t0 + 1), );
        PHASE(0, 2, 0, STAGE_B(0, 0, t0 + 2), );
        PHASE(0, 3, 0, STAGE_B(0, 1, t0 + 2), VMCNT(4));
        PHASE(1, 0, 1, STAGE_A(0, 0, t0 + 2), );
        PHASE(1, 1, 0, STAGE_A(0, 1, t0 + 2), );
        PHASE(1, 2, 0, STAGE_B(1, 0, t0 + 3), );
        PHASE(1, 3, 0, STAGE_B(1, 1, t0 + 3), VMCNT(4));
    }
    // ---- epilogue: tiles 10 (buf0), 11 (buf1); only A11 left to stage.
    //      Entering: [B11 x4]; ph1,2 +A11 -> ph4 VMCNT(0) drains all.
    PHASE(0, 0, 1, STAGE_A(1, 0, 11), );
    PHASE(0, 1, 0, STAGE_A(1, 1, 11), );
    PHASE(0, 2, 0, , );
    PHASE(0, 3, 0, , VMCNT(0));
    PHASE(1, 0, 1, , );
    PHASE(1, 1, 0, , );
    PHASE(1, 2, 0, , );
    PHASE(1, 3, 0, , );

    // ---- coalesced C store via LDS round-trip (tile [256][256] bf16, 128 KiB)
    __syncthreads();
#pragma unroll
    for (int i = 0; i < 8; ++i) {
        const int rloc = wm * 128 + i * 16 + quad * 4;
#pragma unroll
        for (int j = 0; j < 4; ++j) {
            const int cloc = wn * 64 + j * 16 + l16;
            const float bc = bias[n0 + cloc];
#pragma unroll
            for (int r = 0; r < 4; ++r) {
                const int rr = rloc + r;
                int off = (rr * 512 + cloc * 2) ^ ((rr & 4) ? 32 : 0);
                *(bf16*)(smem + off) = __float2bfloat16(acc[i][j][r] + bc);
            }
        }
    }
    __syncthreads();
#pragma unroll
    for (int k = 0; k < 16; ++k) {
        const int off = (k * 512 + tid) * 16;
        const int row = off >> 9;
        const int bcol = (off & 511) ^ ((row & 4) ? 32 : 0);
        if (m0 + row < NNODE) {
            bf16x8 v = *(const bf16x8*)(smem + off);
            *(bf16x8*)(C + (size_t)(m0 + row) * NH + n0 + (bcol >> 1)) = v;
        }
    }
#undef PHASE
#undef MF
#undef LDA8
#undef LDB8
#undef STAGE_A
#undef STAGE_B
}

// ---------------------------------------------------------------------------
// Small-M GEMM for GRU gates: C[128, 2304] f32 = A[128,768] @ Bt[2304,768]^T
// + bias.  Tile 32x256, BK=32, grid (9, 4, 2).  z=0: A = h_ws[vnids[row]]
// (gather fused); z=1: A = memb16.
// ---------------------------------------------------------------------------
__global__ __launch_bounds__(256) void gemm_small(
    const bf16* __restrict__ hws, const int* __restrict__ vnids,
    const bf16* __restrict__ A1, const bf16* __restrict__ B0,
    const bf16* __restrict__ B1, const float* __restrict__ bias0,
    const float* __restrict__ bias1, float* __restrict__ C0,
    float* __restrict__ C1) {
    __shared__ __align__(16) bf16 lA[32 * 32];
    __shared__ __align__(16) bf16 lB[256 * 32];
    const int tid = threadIdx.x;
    const int lane = tid & 63;
    const int wave = tid >> 6;
    const int l16 = lane & 15;
    const int quad = lane >> 4;
    const int K = HDIM;
    const int y0 = blockIdx.y * 32;
    const int x0 = blockIdx.x * 256;
    const bf16* Bt = blockIdx.z ? B1 : B0;
    const float* bias = blockIdx.z ? bias1 : bias0;
    float* C = blockIdx.z ? C1 : C0;

    const int ry = y0 + (tid >> 2);  // 0..127 (valid when tid < 128)
    const bf16* gA;
    if (blockIdx.z)
        gA = A1 + (size_t)ry * K + (tid & 3) * 8;
    else
        gA = hws + (size_t)vnids[ry & 127] * K + (tid & 3) * 8;
    const bf16* gB = Bt + (size_t)(x0 + (tid >> 2)) * K + (tid & 3) * 8;
    bf16* lAp = lA + tid * 8;
    bf16* lBp = lB + tid * 8;
    const size_t rstep = (size_t)64 * K;

    f32x4 acc[2][4];
#pragma unroll
    for (int i = 0; i < 2; ++i)
#pragma unroll
        for (int j = 0; j < 4; ++j) acc[i][j] = (f32x4){0.f, 0.f, 0.f, 0.f};

    for (int k0 = 0; k0 < K; k0 += 32) {
        __syncthreads();
        if (tid < 128) async16(gA + k0, lAp);
        async16(gB + k0, lBp);
        async16(gB + k0 + rstep, lBp + 2048);
        async16(gB + k0 + 2 * rstep, lBp + 4096);
        async16(gB + k0 + 3 * rstep, lBp + 6144);
        __syncthreads();
        bf16x8 af[2], bfr[4];
#pragma unroll
        for (int i = 0; i < 2; ++i)
            af[i] = *(const bf16x8*)(lA + (i * 16 + l16) * 32 + quad * 8);
#pragma unroll
        for (int j = 0; j < 4; ++j)
            bfr[j] = *(const bf16x8*)(lB + (wave * 64 + j * 16 + l16) * 32 +
                                      quad * 8);
#pragma unroll
        for (int i = 0; i < 2; ++i)
#pragma unroll
            for (int j = 0; j < 4; ++j)
                acc[i][j] = __builtin_amdgcn_mfma_f32_16x16x32_bf16(
                    af[i], bfr[j], acc[i][j], 0, 0, 0);
    }

#pragma unroll
    for (int i = 0; i < 2; ++i) {
#pragma unroll
        for (int j = 0; j < 4; ++j) {
            int row = y0 + i * 16 + quad * 4;
            int col = x0 + wave * 64 + j * 16 + l16;
            float bc = bias[col];
#pragma unroll
            for (int r = 0; r < 4; ++r)
                C[(size_t)(row + r) * G3 + col] = acc[i][j][r] + bc;
        }
    }
}

// ---------------------------------------------------------------------------
// Transpose+convert W (K x Nn, f32) -> Wt (Nn x K, bf16), per blockIdx.z.
// ---------------------------------------------------------------------------
__global__ __launch_bounds__(256) void transpose_w(
    const float* __restrict__ W, bf16* __restrict__ Wt, int K, int Nn) {
    __shared__ bf16 tile[64][65];
    const int z = blockIdx.z;
    const float* Wp = W + (size_t)z * K * Nn;
    bf16* Wtp = Wt + (size_t)z * K * Nn;
    const int n0 = blockIdx.x * 64;
    const int k0 = blockIdx.y * 64;
    const int tx = threadIdx.x & 63;
    const int ty = threadIdx.x >> 6;  // 0..3
#pragma unroll
    for (int i = 0; i < 64; i += 4)
        tile[ty + i][tx] = __float2bfloat16(Wp[(size_t)(k0 + ty + i) * Nn + n0 + tx]);
    __syncthreads();
#pragma unroll
    for (int i = 0; i < 64; i += 4)
        Wtp[(size_t)(n0 + ty + i) * K + k0 + tx] = tile[tx][ty + i];
}

// f32 -> bf16 elementwise
__global__ void cvt_kernel(const float* __restrict__ x, bf16* __restrict__ y,
                           int n) {
    int i = blockIdx.x * 256 + threadIdx.x;
    if (i < n) y[i] = __float2bfloat16(x[i]);
}

// ---------------------------------------------------------------------------
// Edge logits: one wave per edge, 8 lanes per head.
// ---------------------------------------------------------------------------
__global__ __launch_bounds__(256) void logits_kernel(
    const bf16* __restrict__ fs, const bf16* __restrict__ fd,
    const float* __restrict__ attn_a_t, const int* __restrict__ src,
    const int* __restrict__ dst, float* __restrict__ logits) {
    __shared__ __align__(16) float s_a[NH];  // 24 KB
    const int tid = threadIdx.x;
    for (int p = tid; p < NH; p += 256) s_a[p] = attn_a_t[p];
    __syncthreads();

    const int wave = tid >> 6;
    const int lane = tid & 63;
    const int e = blockIdx.x * 4 + wave;
    const int gs = src[e], gd = dst[e];
    const bf16* ps = fs + (size_t)gs * NH;
    const bf16* pd = fd + (size_t)gd * NH;
    const int h = lane >> 3;   // head
    const int s = lane & 7;    // sub-lane within head
    const int base = h * HDIM + s * 8;

    float acc = 0.f;
#pragma unroll
    for (int j = 0; j < 12; ++j) {
        const int off = base + j * 64;
        s16x8 a8 = *(const s16x8*)(ps + off);
        s16x8 d8 = *(const s16x8*)(pd + off);
        f32x4 av0 = *(const f32x4*)(s_a + off);
        f32x4 av1 = *(const f32x4*)(s_a + off + 4);
#pragma unroll
        for (int u = 0; u < 4; ++u) {
            float x = b2f(a8[u]) + b2f(d8[u]);
            x = (x > 0.f) ? x : 0.2f * x;
            acc += x * av0[u];
        }
#pragma unroll
        for (int u = 0; u < 4; ++u) {
            float x = b2f(a8[4 + u]) + b2f(d8[4 + u]);
            x = (x > 0.f) ? x : 0.2f * x;
            acc += x * av1[u];
        }
    }
    acc += __shfl_xor(acc, 1);
    acc += __shfl_xor(acc, 2);
    acc += __shfl_xor(acc, 4);
    if (s == 0) logits[(size_t)e * NHEAD + h] = acc;
}

// ---------------------------------------------------------------------------
// Per-molecule edge softmax -> w = a/8; also writes attns output for the
// virtual edges (local edges 96..143, per setup's attn_eids layout).
// ---------------------------------------------------------------------------
__global__ __launch_bounds__(256) void softmax_kernel(
    const float* __restrict__ logits, const int* __restrict__ dst,
    float* __restrict__ w, float* __restrict__ outv) {
    __shared__ float s_logit[EPG * NHEAD];
    __shared__ float s_w[EPG * NHEAD];
    __shared__ int s_ld[EPG];
    __shared__ float s_m[NPG * NHEAD], s_inv[NPG * NHEAD];
    const int tid = threadIdx.x;
    const int b = blockIdx.x;
    for (int p = tid; p < EPG * NHEAD; p += 256)
        s_logit[p] = logits[(size_t)b * EPG * NHEAD + p];
    if (tid < EPG) s_ld[tid] = dst[b * EPG + tid] - b * NPG;
    __syncthreads();

    for (int p = tid; p < NPG * NHEAD; p += 256) {
        int n = p >> 3, h = p & 7;
        float m = -3.0e38f;
        for (int le = 0; le < EPG; ++le)
            if (s_ld[le] == n) m = fmaxf(m, s_logit[le * NHEAD + h]);
        float ss = 0.f;
        for (int le = 0; le < EPG; ++le)
            if (s_ld[le] == n) ss += __expf(s_logit[le * NHEAD + h] - m);
        s_m[p] = m;
        s_inv[p] = (ss > 0.f) ? 1.f / ss : 0.f;
    }
    __syncthreads();

    for (int p = tid; p < EPG * NHEAD; p += 256) {
        int le = p >> 3, h = p & 7;
        int ld = s_ld[le];
        float a =
            0.125f * __expf(s_logit[p] - s_m[ld * NHEAD + h]) * s_inv[ld * NHEAD + h];
        s_w[p] = a;
        w[(size_t)b * EPG * NHEAD + p] = a;
    }
    __syncthreads();
    // attns[t][b*48+i] = sum_h w[edge 96+i, h]
    if (tid < 48) {
        float s = 0.f;
#pragma unroll
        for (int h = 0; h < NHEAD; ++h) s += s_w[(96 + tid) * NHEAD + h];
        outv[b * 48 + tid] = s;
    }
}

// ---------------------------------------------------------------------------
// h_next[n,j] = sum_{e: dst=n} sum_h w[e,h] * fs[src_e, h*HDIM + j]
// grid (6 chunks of 128 dims, BMOL); 4 edge-groups x 64 lanes, 2 dims/thread
// (s16x2 loads: 4 B/lane, 256 B/wave coalesced); LDS f32 atomics.
// ---------------------------------------------------------------------------
__global__ __launch_bounds__(256) void aggregate_kernel(
    const bf16* __restrict__ fs, const float* __restrict__ w,
    const int* __restrict__ src, const int* __restrict__ dst,
    bf16* __restrict__ hout) {
    __shared__ float acc[NPG * 128];      // 25 KB
    __shared__ float s_w[EPG * NHEAD];    // 4.5 KB
    __shared__ int s_gs[EPG], s_ld[EPG];
    const int tid = threadIdx.x;
    const int c = blockIdx.x;
    const int b = blockIdx.y;
    const int grp = tid >> 6;   // edge group 0..3
    const int l = tid & 63;     // dim-pair lane
    if (tid < EPG) {
        int e = b * EPG + tid;
        s_gs[tid] = src[e];
        s_ld[tid] = dst[e] - b * NPG;
    }
    for (int p = tid; p < EPG * NHEAD; p += 256)
        s_w[p] = w[(size_t)b * EPG * NHEAD + p];
    for (int p = tid; p < NPG * 128; p += 256) acc[p] = 0.f;
    __syncthreads();

    const int dim = c * 128 + l * 2;
    for (int le4 = 0; le4 < EPG; le4 += 4) {
        const int le = le4 + grp;
        const bf16* p = fs + (size_t)s_gs[le] * NH + dim;
        float sum0 = 0.f, sum1 = 0.f;
#pragma unroll
        for (int h = 0; h < NHEAD; ++h) {
            s16x2 v = *(const s16x2*)(p + h * HDIM);
            float wv = s_w[le * NHEAD + h];
            sum0 += wv * b2f(v[0]);
            sum1 += wv * b2f(v[1]);
        }
        float* ap = &acc[s_ld[le] * 128 + l * 2];
        atomicAdd(ap, sum0);
        atomicAdd(ap + 1, sum1);
    }
    __syncthreads();
    for (int p = tid; p < NPG * 128; p += 256) {
        int n = p >> 7, d = p & 127;
        hout[((size_t)b * NPG + n) * HDIM + c * 128 + d] =
            __float2bfloat16(acc[p]);
    }
}

__global__ void init_memb_kernel(const float* __restrict__ mf,
                                 float* __restrict__ m32,
                                 bf16* __restrict__ m16) {
    int idx = blockIdx.x * 256 + threadIdx.x;
    float f = mf[idx];
    m32[idx] = f;
    m16[idx] = __float2bfloat16(f);
}

// GRU gates (r,z,n) + relu
__global__ void gru_gate_kernel(const float* __restrict__ gi,
                                const float* __restrict__ gh,
                                float* __restrict__ m32, bf16* __restrict__ m16,
                                float* __restrict__ outp, int last) {
    int idx = blockIdx.x * 256 + threadIdx.x;  // < BMOL*HDIM
    int b = idx / HDIM, d = idx - b * HDIM;
    const float* gib = gi + (size_t)b * G3;
    const float* ghb = gh + (size_t)b * G3;
    float ir = gib[d], iz = gib[HDIM + d], in_ = gib[2 * HDIM + d];
    float hr = ghb[d], hz = ghb[HDIM + d], hn = ghb[2 * HDIM + d];
    float r = 1.f / (1.f + __expf(-(ir + hr)));
    float z = 1.f / (1.f + __expf(-(iz + hz)));
    float n = tanhf(in_ + r * hn);
    float hprev = m32[idx];
    float hnew = (1.f - z) * n + z * hprev;
    hnew = fmaxf(hnew, 0.f);  // relu
    m32[idx] = hnew;
    m16[idx] = __float2bfloat16(hnew);
    if (last) outp[idx] = hnew;
}

// ---------------------------------------------------------------------------
extern "C" void kernel_launch(void* const* d_in, const int* in_sizes, int n_in,
                              void* d_out, int out_size, void* d_ws,
                              size_t ws_size, hipStream_t stream) {
    const float* h_nodes = (const float*)d_in[0];
    const float* mol_feat = (const float*)d_in[1];
    const float* W_src = (const float*)d_in[2];
    const float* b_src = (const float*)d_in[3];
    const float* W_dst = (const float*)d_in[4];
    const float* b_dst = (const float*)d_in[5];
    const float* attn_a = (const float*)d_in[6];
    const float* W_ih = (const float*)d_in[7];
    const float* W_hh = (const float*)d_in[8];
    const float* b_ih = (const float*)d_in[9];
    const float* b_hh = (const float*)d_in[10];
    const int* src = (const int*)d_in[11];
    const int* dst = (const int*)d_in[12];
    const int* vnids = (const int*)d_in[13];
    float* out = (float*)d_out;

    char* p = (char*)d_ws;
    auto alloc = [&](size_t bytes) {
        char* r = p;
        p += (bytes + 255) & ~(size_t)255;
        return r;
    };
    bf16* wsrcT = (bf16*)alloc((size_t)3 * NH * HDIM * 2);
    bf16* wdstT = (bf16*)alloc((size_t)3 * NH * HDIM * 2);
    bf16* wihB = (bf16*)alloc((size_t)3 * G3 * HDIM * 2);
    bf16* whhB = (bf16*)alloc((size_t)3 * G3 * HDIM * 2);
    bf16* fs = (bf16*)alloc((size_t)NNODE * NH * 2);
    bf16* fd = (bf16*)alloc((size_t)NNODE * NH * 2);
    bf16* h_ws = (bf16*)alloc((size_t)NNODE * HDIM * 2);
    float* lg = (float*)alloc((size_t)NEDGE * NHEAD * 4);
    float* w_e = (float*)alloc((size_t)NEDGE * NHEAD * 4);
    float* memb32 = (float*)alloc((size_t)BMOL * HDIM * 4);
    bf16* memb16 = (bf16*)alloc((size_t)BMOL * HDIM * 2);
    float* gi = (float*)alloc((size_t)BMOL * G3 * 4);
    float* gh = (float*)alloc((size_t)BMOL * G3 * 4);

    dim3 tgrid(NH / 64, HDIM / 64, 3);
    transpose_w<<<tgrid, 256, 0, stream>>>(W_src, wsrcT, HDIM, NH);
    transpose_w<<<tgrid, 256, 0, stream>>>(W_dst, wdstT, HDIM, NH);
    {
        int n = 3 * G3 * HDIM;
        cvt_kernel<<<(n + 255) / 256, 256, 0, stream>>>(W_ih, wihB, n);
        cvt_kernel<<<(n + 255) / 256, 256, 0, stream>>>(W_hh, whhB, n);
    }
    {
        int n = NNODE * HDIM;
        cvt_kernel<<<(n + 255) / 256, 256, 0, stream>>>(h_nodes, h_ws, n);
    }
    init_memb_kernel<<<BMOL * HDIM / 256, 256, 0, stream>>>(mol_feat, memb32,
                                                            memb16);

    for (int t = 0; t < 3; ++t) {
        gemm_bt8<<<dim3(24, 25, 2), 512, 0, stream>>>(
            h_ws, wsrcT + (size_t)t * NH * HDIM, wdstT + (size_t)t * NH * HDIM,
            b_src + (size_t)t * NH, b_dst + (size_t)t * NH, fs, fd);
        logits_kernel<<<NEDGE / 4, 256, 0, stream>>>(
            fs, fd, attn_a + (size_t)t * NHEAD * HDIM, src, dst, lg);
        softmax_kernel<<<BMOL, 256, 0, stream>>>(
            lg, dst, w_e, out + BMOL * HDIM + t * BMOL * 48);
        aggregate_kernel<<<dim3(6, BMOL), 256, 0, stream>>>(fs, w_e, src, dst,
                                                            h_ws);
        gemm_small<<<dim3(G3 / 256, 4, 2), 256, 0, stream>>>(
            h_ws, vnids, memb16, wihB + (size_t)t * G3 * HDIM,
            whhB + (size_t)t * G3 * HDIM, b_ih + (size_t)t * G3,
            b_hh + (size_t)t * G3, gi, gh);
        gru_gate_kernel<<<BMOL * HDIM / 256, 256, 0, stream>>>(
            gi, gh, memb32, memb16, out, t == 2);
    }
}

// Round 6
// 1044.662 us; speedup vs baseline: 1.1682x; 1.1682x over previous
//
#include <hip/hip_runtime.h>
#include <hip/hip_bf16.h>

typedef __hip_bfloat16 bf16;
typedef float f32x4 __attribute__((ext_vector_type(4)));
typedef __bf16 bf16x8 __attribute__((ext_vector_type(8)));
typedef short s16x8 __attribute__((ext_vector_type(8)));
typedef short s16x2 __attribute__((ext_vector_type(2)));

#define HDIM 768
#define NHEAD 8
#define BMOL 128
#define NPG 49
#define EPG 144
#define NNODE (BMOL * NPG)     /* 6272 */
#define NEDGE (BMOL * EPG)     /* 18432 */
#define NH 6144                /* NHEAD*HDIM */
#define G3 2304                /* 3*HDIM */

__device__ __forceinline__ float b2f(short s) {
    unsigned int u = ((unsigned int)(unsigned short)s) << 16;
    return __builtin_bit_cast(float, u);
}

__device__ __forceinline__ void async16(const bf16* g, bf16* l) {
    __builtin_amdgcn_global_load_lds(
        (const __attribute__((address_space(1))) void*)g,
        (__attribute__((address_space(3))) void*)l, 16, 0, 0);
}

#define VMCNT(n) asm volatile("s_waitcnt vmcnt(" #n ")" ::: "memory")
#define SBAR()                                 \
    do {                                       \
        asm volatile("" ::: "memory");         \
        __builtin_amdgcn_s_barrier();          \
        asm volatile("" ::: "memory");         \
    } while (0)

// ---------------------------------------------------------------------------
// 256x256-tile 8-phase bf16 GEMM (unchanged from the passing r5 version).
// C[M,N] = A[M,K] @ Bt[N,K]^T + bias[N], K = 768 (12 K-tiles of 64).
// At t=2 launched with gridDim.z=1 (fs plane only; fd not needed then).
// ---------------------------------------------------------------------------
__global__ __launch_bounds__(512, 2) void gemm_bt8(
    const bf16* __restrict__ A, const bf16* __restrict__ Bt0,
    const bf16* __restrict__ Bt1, const float* __restrict__ bias0,
    const float* __restrict__ bias1, bf16* __restrict__ C0,
    bf16* __restrict__ C1) {
    __shared__ __align__(16) char smem[131072];
    bf16* lA = (bf16*)smem;                // [2 buf][2 half][8192]  64 KiB
    bf16* lB = (bf16*)(smem + 65536);      // same                  64 KiB

    const int tid = threadIdx.x;
    const int lane = tid & 63;
    const int wave = tid >> 6;
    const int l16 = lane & 15;
    const int quad = lane >> 4;
    const int wm = wave >> 2;  // 0..1
    const int wn = wave & 3;   // 0..3
    const int K = HDIM;

    // A-chunk-resident bijective XCD walk (600 tiles/plane, 600 % 8 == 0)
    int id = blockIdx.y * 24 + blockIdx.x;
    const int xcd = id & 7;
    const int loc = id >> 3;          // 0..74
    const int mc = loc / 15;          // 0..4  A-chunk
    const int rem = loc % 15;
    const int ncol = rem / 5;         // 0..2
    const int moff = rem % 5;         // 0..4
    const int m0 = (mc * 5 + moff) * 256;
    const int n0 = (xcd * 3 + ncol) * 256;

    const bf16* Bt = blockIdx.z ? Bt1 : Bt0;
    const float* bias = blockIdx.z ? bias1 : bias0;
    bf16* C = blockIdx.z ? C1 : C0;

    const int srow = tid >> 3;  // 0..63 (row within 64-row chunk)
    const int ecol =
        ((tid & 7) * 8) ^ ((srow & 1) * 32) ^ ((srow & 2) * 8);
    const bf16* gAr[4];
#pragma unroll
    for (int hc = 0; hc < 4; ++hc) {
        int r = m0 + srow + hc * 64;
        if (r > NNODE - 1) r = NNODE - 1;
        gAr[hc] = A + (size_t)r * K + ecol;
    }
    const bf16* gB = Bt + (size_t)(n0 + srow) * K + ecol;
    const size_t hstep = (size_t)128 * K;  // half-panel row step
    const size_t cstep = (size_t)64 * K;   // chunk row step
    bf16* dA = lA + tid * 8;  // + buf*16384 + h*8192 (elements)
    bf16* dB = lB + tid * 8;

#define STAGE_A(buf, h, kt)                                     \
    do {                                                        \
        bf16* _d = dA + (buf)*16384 + (h)*8192;                 \
        async16(gAr[(h)*2] + (size_t)(kt) * 64, _d);            \
        async16(gAr[(h)*2 + 1] + (size_t)(kt) * 64, _d + 4096); \
    } while (0)
#define STAGE_B(buf, h, kt)                                     \
    do {                                                        \
        const bf16* _s = gB + (h)*hstep + (size_t)(kt) * 64;    \
        bf16* _d = dB + (buf)*16384 + (h)*8192;                 \
        async16(_s, _d);                                        \
        async16(_s + cstep, _d + 4096);                         \
    } while (0)

    const int q16 = quad * 16;
    const int sw = ((l16 & 1) << 6) | ((l16 & 2) << 4);
    const char* laRow = (const char*)lA + wm * 16384 + l16 * 128;
    const char* lbRow =
        (const char*)lB + (wn >> 1) * 16384 + (wn & 1) * 8192 + l16 * 128;

#define LDA8(buf, f, ks) \
    (*(const bf16x8*)(laRow + (buf)*32768 + (f)*2048 + ((q16 + (ks)*64) ^ sw)))
#define LDB8(buf, j, ks) \
    (*(const bf16x8*)(lbRow + (buf)*32768 + (j)*2048 + ((q16 + (ks)*64) ^ sw)))

    f32x4 acc[8][4];
#pragma unroll
    for (int i = 0; i < 8; ++i)
#pragma unroll
        for (int j = 0; j < 4; ++j) acc[i][j] = (f32x4){0.f, 0.f, 0.f, 0.f};
    bf16x8 bfr[4][2];

#define MF(i, j, ks, areg)                                             \
    acc[i][j] = __builtin_amdgcn_mfma_f32_16x16x32_bf16(areg, bfr[j][ks], \
                                                        acc[i][j], 0, 0, 0)

#define PHASE(buf, q, LB, STG, WAIT)                                   \
    do {                                                               \
        bf16x8 a00 = LDA8(buf, (q)*2, 0);                              \
        bf16x8 a01 = LDA8(buf, (q)*2, 1);                              \
        bf16x8 a10 = LDA8(buf, (q)*2 + 1, 0);                          \
        bf16x8 a11 = LDA8(buf, (q)*2 + 1, 1);                          \
        if (LB) {                                                      \
            bfr[0][0] = LDB8(buf, 0, 0); bfr[0][1] = LDB8(buf, 0, 1);  \
            bfr[1][0] = LDB8(buf, 1, 0); bfr[1][1] = LDB8(buf, 1, 1);  \
            bfr[2][0] = LDB8(buf, 2, 0); bfr[2][1] = LDB8(buf, 2, 1);  \
            bfr[3][0] = LDB8(buf, 3, 0); bfr[3][1] = LDB8(buf, 3, 1);  \
        }                                                              \
        STG;                                                           \
        SBAR();                                                        \
        __builtin_amdgcn_s_setprio(1);                                 \
        MF((q)*2, 0, 0, a00); MF((q)*2, 1, 0, a00);                    \
        MF((q)*2, 2, 0, a00); MF((q)*2, 3, 0, a00);                    \
        MF((q)*2 + 1, 0, 0, a10); MF((q)*2 + 1, 1, 0, a10);            \
        MF((q)*2 + 1, 2, 0, a10); MF((q)*2 + 1, 3, 0, a10);            \
        MF((q)*2, 0, 1, a01); MF((q)*2, 1, 1, a01);                    \
        MF((q)*2, 2, 1, a01); MF((q)*2, 3, 1, a01);                    \
        MF((q)*2 + 1, 0, 1, a11); MF((q)*2 + 1, 1, 1, a11);            \
        MF((q)*2 + 1, 2, 1, a11); MF((q)*2 + 1, 3, 1, a11);            \
        __builtin_amdgcn_s_setprio(0);                                 \
        WAIT;                                                          \
        SBAR();                                                        \
    } while (0)

    // ---- prologue
    STAGE_A(0, 0, 0); STAGE_A(0, 1, 0);
    STAGE_B(0, 0, 0); STAGE_B(0, 1, 0);
    STAGE_B(1, 0, 1); STAGE_B(1, 1, 1);
    VMCNT(4);
    SBAR();

    int t0 = 0;
    for (int it = 0; it < 5; ++it, t0 += 2) {
        PHASE(0, 0, 1, STAGE_A(1, 0, t0 + 1), );
        PHASE(0, 1, 0, STAGE_A(1, 1, t0 + 1), );
        PHASE(0, 2, 0, STAGE_B(0, 0, t0 + 2), );
        PHASE(0, 3, 0, STAGE_B(0, 1, t0 + 2), VMCNT(4));
        PHASE(1, 0, 1, STAGE_A(0, 0, t0 + 2), );
        PHASE(1, 1, 0, STAGE_A(0, 1, t0 + 2), );
        PHASE(1, 2, 0, STAGE_B(1, 0, t0 + 3), );
        PHASE(1, 3, 0, STAGE_B(1, 1, t0 + 3), VMCNT(4));
    }
    PHASE(0, 0, 1, STAGE_A(1, 0, 11), );
    PHASE(0, 1, 0, STAGE_A(1, 1, 11), );
    PHASE(0, 2, 0, , );
    PHASE(0, 3, 0, , VMCNT(0));
    PHASE(1, 0, 1, , );
    PHASE(1, 1, 0, , );
    PHASE(1, 2, 0, , );
    PHASE(1, 3, 0, , );

    // ---- coalesced C store via LDS round-trip
    __syncthreads();
#pragma unroll
    for (int i = 0; i < 8; ++i) {
        const int rloc = wm * 128 + i * 16 + quad * 4;
#pragma unroll
        for (int j = 0; j < 4; ++j) {
            const int cloc = wn * 64 + j * 16 + l16;
            const float bc = bias[n0 + cloc];
#pragma unroll
            for (int r = 0; r < 4; ++r) {
                const int rr = rloc + r;
                int off = (rr * 512 + cloc * 2) ^ ((rr & 4) ? 32 : 0);
                *(bf16*)(smem + off) = __float2bfloat16(acc[i][j][r] + bc);
            }
        }
    }
    __syncthreads();
#pragma unroll
    for (int k = 0; k < 16; ++k) {
        const int off = (k * 512 + tid) * 16;
        const int row = off >> 9;
        const int bcol = (off & 511) ^ ((row & 4) ? 32 : 0);
        if (m0 + row < NNODE) {
            bf16x8 v = *(const bf16x8*)(smem + off);
            *(bf16x8*)(C + (size_t)(m0 + row) * NH + n0 + (bcol >> 1)) = v;
        }
    }
#undef PHASE
#undef MF
#undef LDA8
#undef LDB8
#undef STAGE_A
#undef STAGE_B
}

// ---------------------------------------------------------------------------
// Small-M GEMM for GRU gates: C[128, 2304] f32 = A[128,768] @ Bt[2304,768]^T
// + bias.  Tile 32x256, BK=32, grid (9, 4, 2).  z=0: A = A0 rows if A0 else
// h_ws[vnids[row]] (gather); z=1: A = memb16.
// ---------------------------------------------------------------------------
__global__ __launch_bounds__(256) void gemm_small(
    const bf16* __restrict__ hws, const int* __restrict__ vnids,
    const bf16* __restrict__ A1, const bf16* __restrict__ B0,
    const bf16* __restrict__ B1, const float* __restrict__ bias0,
    const float* __restrict__ bias1, float* __restrict__ C0,
    float* __restrict__ C1, const bf16* __restrict__ A0) {
    __shared__ __align__(16) bf16 lA[32 * 32];
    __shared__ __align__(16) bf16 lB[256 * 32];
    const int tid = threadIdx.x;
    const int lane = tid & 63;
    const int wave = tid >> 6;
    const int l16 = lane & 15;
    const int quad = lane >> 4;
    const int K = HDIM;
    const int y0 = blockIdx.y * 32;
    const int x0 = blockIdx.x * 256;
    const bf16* Bt = blockIdx.z ? B1 : B0;
    const float* bias = blockIdx.z ? bias1 : bias0;
    float* C = blockIdx.z ? C1 : C0;

    const int ry = y0 + (tid >> 2);  // 0..127 (valid when tid < 128)
    const bf16* gA;
    if (blockIdx.z)
        gA = A1 + (size_t)ry * K + (tid & 3) * 8;
    else if (A0)
        gA = A0 + (size_t)(ry & 127) * K + (tid & 3) * 8;
    else
        gA = hws + (size_t)vnids[ry & 127] * K + (tid & 3) * 8;
    const bf16* gB = Bt + (size_t)(x0 + (tid >> 2)) * K + (tid & 3) * 8;
    bf16* lAp = lA + tid * 8;
    bf16* lBp = lB + tid * 8;
    const size_t rstep = (size_t)64 * K;

    f32x4 acc[2][4];
#pragma unroll
    for (int i = 0; i < 2; ++i)
#pragma unroll
        for (int j = 0; j < 4; ++j) acc[i][j] = (f32x4){0.f, 0.f, 0.f, 0.f};

    for (int k0 = 0; k0 < K; k0 += 32) {
        __syncthreads();
        if (tid < 128) async16(gA + k0, lAp);
        async16(gB + k0, lBp);
        async16(gB + k0 + rstep, lBp + 2048);
        async16(gB + k0 + 2 * rstep, lBp + 4096);
        async16(gB + k0 + 3 * rstep, lBp + 6144);
        __syncthreads();
        bf16x8 af[2], bfr[4];
#pragma unroll
        for (int i = 0; i < 2; ++i)
            af[i] = *(const bf16x8*)(lA + (i * 16 + l16) * 32 + quad * 8);
#pragma unroll
        for (int j = 0; j < 4; ++j)
            bfr[j] = *(const bf16x8*)(lB + (wave * 64 + j * 16 + l16) * 32 +
                                      quad * 8);
#pragma unroll
        for (int i = 0; i < 2; ++i)
#pragma unroll
            for (int j = 0; j < 4; ++j)
                acc[i][j] = __builtin_amdgcn_mfma_f32_16x16x32_bf16(
                    af[i], bfr[j], acc[i][j], 0, 0, 0);
    }

#pragma unroll
    for (int i = 0; i < 2; ++i) {
#pragma unroll
        for (int j = 0; j < 4; ++j) {
            int row = y0 + i * 16 + quad * 4;
            int col = x0 + wave * 64 + j * 16 + l16;
            float bc = bias[col];
#pragma unroll
            for (int r = 0; r < 4; ++r)
                C[(size_t)(row + r) * G3 + col] = acc[i][j][r] + bc;
        }
    }
}

// ---------------------------------------------------------------------------
// fd_virt[128, NH] bf16 = h_ws[vnids[r]] @ Bt^T + bias (t=2 only; fd is
// needed solely for the 128 virtual rows then).  Tile 32x256, grid (24, 4).
// ---------------------------------------------------------------------------
__global__ __launch_bounds__(256) void gemm_gather_bt(
    const bf16* __restrict__ hws, const int* __restrict__ vnids,
    const bf16* __restrict__ Bt, const float* __restrict__ bias,
    bf16* __restrict__ C) {
    __shared__ __align__(16) bf16 lA[32 * 32];
    __shared__ __align__(16) bf16 lB[256 * 32];
    const int tid = threadIdx.x;
    const int lane = tid & 63;
    const int wave = tid >> 6;
    const int l16 = lane & 15;
    const int quad = lane >> 4;
    const int K = HDIM;
    const int y0 = blockIdx.y * 32;
    const int x0 = blockIdx.x * 256;

    const int ry = y0 + (tid >> 2);
    const bf16* gA = hws + (size_t)vnids[ry & 127] * K + (tid & 3) * 8;
    const bf16* gB = Bt + (size_t)(x0 + (tid >> 2)) * K + (tid & 3) * 8;
    bf16* lAp = lA + tid * 8;
    bf16* lBp = lB + tid * 8;
    const size_t rstep = (size_t)64 * K;

    f32x4 acc[2][4];
#pragma unroll
    for (int i = 0; i < 2; ++i)
#pragma unroll
        for (int j = 0; j < 4; ++j) acc[i][j] = (f32x4){0.f, 0.f, 0.f, 0.f};

    for (int k0 = 0; k0 < K; k0 += 32) {
        __syncthreads();
        if (tid < 128) async16(gA + k0, lAp);
        async16(gB + k0, lBp);
        async16(gB + k0 + rstep, lBp + 2048);
        async16(gB + k0 + 2 * rstep, lBp + 4096);
        async16(gB + k0 + 3 * rstep, lBp + 6144);
        __syncthreads();
        bf16x8 af[2], bfr[4];
#pragma unroll
        for (int i = 0; i < 2; ++i)
            af[i] = *(const bf16x8*)(lA + (i * 16 + l16) * 32 + quad * 8);
#pragma unroll
        for (int j = 0; j < 4; ++j)
            bfr[j] = *(const bf16x8*)(lB + (wave * 64 + j * 16 + l16) * 32 +
                                      quad * 8);
#pragma unroll
        for (int i = 0; i < 2; ++i)
#pragma unroll
            for (int j = 0; j < 4; ++j)
                acc[i][j] = __builtin_amdgcn_mfma_f32_16x16x32_bf16(
                    af[i], bfr[j], acc[i][j], 0, 0, 0);
    }

#pragma unroll
    for (int i = 0; i < 2; ++i) {
#pragma unroll
        for (int j = 0; j < 4; ++j) {
            int row = y0 + i * 16 + quad * 4;
            int col = x0 + wave * 64 + j * 16 + l16;
            float bc = bias[col];
#pragma unroll
            for (int r = 0; r < 4; ++r)
                C[(size_t)(row + r) * NH + col] =
                    __float2bfloat16(acc[i][j][r] + bc);
        }
    }
}

// ---------------------------------------------------------------------------
// Transpose+convert W (K x Nn, f32) -> Wt (Nn x K, bf16), per blockIdx.z.
// ---------------------------------------------------------------------------
__global__ __launch_bounds__(256) void transpose_w(
    const float* __restrict__ W, bf16* __restrict__ Wt, int K, int Nn) {
    __shared__ bf16 tile[64][65];
    const int z = blockIdx.z;
    const float* Wp = W + (size_t)z * K * Nn;
    bf16* Wtp = Wt + (size_t)z * K * Nn;
    const int n0 = blockIdx.x * 64;
    const int k0 = blockIdx.y * 64;
    const int tx = threadIdx.x & 63;
    const int ty = threadIdx.x >> 6;  // 0..3
#pragma unroll
    for (int i = 0; i < 64; i += 4)
        tile[ty + i][tx] = __float2bfloat16(Wp[(size_t)(k0 + ty + i) * Nn + n0 + tx]);
    __syncthreads();
#pragma unroll
    for (int i = 0; i < 64; i += 4)
        Wtp[(size_t)(n0 + ty + i) * K + k0 + tx] = tile[tx][ty + i];
}

// f32 -> bf16 elementwise
__global__ void cvt_kernel(const float* __restrict__ x, bf16* __restrict__ y,
                           int n) {
    int i = blockIdx.x * 256 + threadIdx.x;
    if (i < n) y[i] = __float2bfloat16(x[i]);
}

// ---------------------------------------------------------------------------
// Edge logits: one wave per edge, 8 lanes per head.
// ---------------------------------------------------------------------------
__global__ __launch_bounds__(256) void logits_kernel(
    const bf16* __restrict__ fs, const bf16* __restrict__ fd,
    const float* __restrict__ attn_a_t, const int* __restrict__ src,
    const int* __restrict__ dst, float* __restrict__ logits) {
    __shared__ __align__(16) float s_a[NH];  // 24 KB
    const int tid = threadIdx.x;
    for (int p = tid; p < NH; p += 256) s_a[p] = attn_a_t[p];
    __syncthreads();

    const int wave = tid >> 6;
    const int lane = tid & 63;
    const int e = blockIdx.x * 4 + wave;
    const int gs = src[e], gd = dst[e];
    const bf16* ps = fs + (size_t)gs * NH;
    const bf16* pd = fd + (size_t)gd * NH;
    const int h = lane >> 3;   // head
    const int s = lane & 7;    // sub-lane within head
    const int base = h * HDIM + s * 8;

    float acc = 0.f;
#pragma unroll
    for (int j = 0; j < 12; ++j) {
        const int off = base + j * 64;
        s16x8 a8 = *(const s16x8*)(ps + off);
        s16x8 d8 = *(const s16x8*)(pd + off);
        f32x4 av0 = *(const f32x4*)(s_a + off);
        f32x4 av1 = *(const f32x4*)(s_a + off + 4);
#pragma unroll
        for (int u = 0; u < 4; ++u) {
            float x = b2f(a8[u]) + b2f(d8[u]);
            x = (x > 0.f) ? x : 0.2f * x;
            acc += x * av0[u];
        }
#pragma unroll
        for (int u = 0; u < 4; ++u) {
            float x = b2f(a8[4 + u]) + b2f(d8[4 + u]);
            x = (x > 0.f) ? x : 0.2f * x;
            acc += x * av1[u];
        }
    }
    acc += __shfl_xor(acc, 1);
    acc += __shfl_xor(acc, 2);
    acc += __shfl_xor(acc, 4);
    if (s == 0) logits[(size_t)e * NHEAD + h] = acc;
}

// ---------------------------------------------------------------------------
// t=2: logits only for virtual edges.  Edge e in [0,6144): b=e/48, i=e%48;
// src row = b*49+i (setup: virt_src ordered), dst = virtual -> fdv[b].
// ---------------------------------------------------------------------------
__global__ __launch_bounds__(256) void logits_virt_kernel(
    const bf16* __restrict__ fs, const bf16* __restrict__ fdv,
    const float* __restrict__ attn_a_t, float* __restrict__ lgv) {
    __shared__ __align__(16) float s_a[NH];
    const int tid = threadIdx.x;
    for (int p = tid; p < NH; p += 256) s_a[p] = attn_a_t[p];
    __syncthreads();

    const int wave = tid >> 6;
    const int lane = tid & 63;
    const int e = blockIdx.x * 4 + wave;  // 0..6143
    const int b = e / 48;
    const int i = e - b * 48;
    const bf16* ps = fs + (size_t)(b * NPG + i) * NH;
    const bf16* pd = fdv + (size_t)b * NH;
    const int h = lane >> 3;
    const int s = lane & 7;
    const int base = h * HDIM + s * 8;

    float acc = 0.f;
#pragma unroll
    for (int j = 0; j < 12; ++j) {
        const int off = base + j * 64;
        s16x8 a8 = *(const s16x8*)(ps + off);
        s16x8 d8 = *(const s16x8*)(pd + off);
        f32x4 av0 = *(const f32x4*)(s_a + off);
        f32x4 av1 = *(const f32x4*)(s_a + off + 4);
#pragma unroll
        for (int u = 0; u < 4; ++u) {
            float x = b2f(a8[u]) + b2f(d8[u]);
            x = (x > 0.f) ? x : 0.2f * x;
            acc += x * av0[u];
        }
#pragma unroll
        for (int u = 0; u < 4; ++u) {
            float x = b2f(a8[4 + u]) + b2f(d8[4 + u]);
            x = (x > 0.f) ? x : 0.2f * x;
            acc += x * av1[u];
        }
    }
    acc += __shfl_xor(acc, 1);
    acc += __shfl_xor(acc, 2);
    acc += __shfl_xor(acc, 4);
    if (s == 0) lgv[(size_t)e * NHEAD + h] = acc;
}

// ---------------------------------------------------------------------------
// Per-molecule edge softmax -> w = a/8; also writes attns output for the
// virtual edges (local edges 96..143, per setup's attn_eids layout).
// ---------------------------------------------------------------------------
__global__ __launch_bounds__(256) void softmax_kernel(
    const float* __restrict__ logits, const int* __restrict__ dst,
    float* __restrict__ w, float* __restrict__ outv) {
    __shared__ float s_logit[EPG * NHEAD];
    __shared__ float s_w[EPG * NHEAD];
    __shared__ int s_ld[EPG];
    __shared__ float s_m[NPG * NHEAD], s_inv[NPG * NHEAD];
    const int tid = threadIdx.x;
    const int b = blockIdx.x;
    for (int p = tid; p < EPG * NHEAD; p += 256)
        s_logit[p] = logits[(size_t)b * EPG * NHEAD + p];
    if (tid < EPG) s_ld[tid] = dst[b * EPG + tid] - b * NPG;
    __syncthreads();

    for (int p = tid; p < NPG * NHEAD; p += 256) {
        int n = p >> 3, h = p & 7;
        float m = -3.0e38f;
        for (int le = 0; le < EPG; ++le)
            if (s_ld[le] == n) m = fmaxf(m, s_logit[le * NHEAD + h]);
        float ss = 0.f;
        for (int le = 0; le < EPG; ++le)
            if (s_ld[le] == n) ss += __expf(s_logit[le * NHEAD + h] - m);
        s_m[p] = m;
        s_inv[p] = (ss > 0.f) ? 1.f / ss : 0.f;
    }
    __syncthreads();

    for (int p = tid; p < EPG * NHEAD; p += 256) {
        int le = p >> 3, h = p & 7;
        int ld = s_ld[le];
        float a =
            0.125f * __expf(s_logit[p] - s_m[ld * NHEAD + h]) * s_inv[ld * NHEAD + h];
        s_w[p] = a;
        w[(size_t)b * EPG * NHEAD + p] = a;
    }
    __syncthreads();
    // attns[t][b*48+i] = sum_h w[edge 96+i, h]
    if (tid < 48) {
        float s = 0.f;
#pragma unroll
        for (int h = 0; h < NHEAD; ++h) s += s_w[(96 + tid) * NHEAD + h];
        outv[b * 48 + tid] = s;
    }
}

// ---------------------------------------------------------------------------
// t=2: softmax over the 48 virtual edges per mol (their dst group is exactly
// these edges).  Writes wv = a/8 and attns out.  Grid (BMOL), 64 threads.
// ---------------------------------------------------------------------------
__global__ __launch_bounds__(64) void softmax_virt_kernel(
    const float* __restrict__ lgv, float* __restrict__ wv,
    float* __restrict__ outv) {
    __shared__ float s_w[48 * NHEAD];
    const int b = blockIdx.x;
    const int tid = threadIdx.x;
    if (tid < NHEAD) {
        const int h = tid;
        float m = -3.0e38f;
        for (int i = 0; i < 48; ++i)
            m = fmaxf(m, lgv[(size_t)(b * 48 + i) * NHEAD + h]);
        float ss = 0.f;
        for (int i = 0; i < 48; ++i)
            ss += __expf(lgv[(size_t)(b * 48 + i) * NHEAD + h] - m);
        float inv = (ss > 0.f) ? 1.f / ss : 0.f;
        for (int i = 0; i < 48; ++i) {
            float a =
                0.125f * __expf(lgv[(size_t)(b * 48 + i) * NHEAD + h] - m) * inv;
            s_w[i * NHEAD + h] = a;
            wv[(size_t)(b * 48 + i) * NHEAD + h] = a;
        }
    }
    __syncthreads();
    if (tid < 48) {
        float s = 0.f;
#pragma unroll
        for (int h = 0; h < NHEAD; ++h) s += s_w[tid * NHEAD + h];
        outv[b * 48 + tid] = s;
    }
}

// ---------------------------------------------------------------------------
// h_next[n,j] = sum_{e: dst=n} sum_h w[e,h] * fs[src_e, h*HDIM + j]
// grid (6 chunks of 128 dims, BMOL).
// ---------------------------------------------------------------------------
__global__ __launch_bounds__(256) void aggregate_kernel(
    const bf16* __restrict__ fs, const float* __restrict__ w,
    const int* __restrict__ src, const int* __restrict__ dst,
    bf16* __restrict__ hout) {
    __shared__ float acc[NPG * 128];      // 25 KB
    __shared__ float s_w[EPG * NHEAD];    // 4.5 KB
    __shared__ int s_gs[EPG], s_ld[EPG];
    const int tid = threadIdx.x;
    const int c = blockIdx.x;
    const int b = blockIdx.y;
    const int grp = tid >> 6;   // edge group 0..3
    const int l = tid & 63;     // dim-pair lane
    if (tid < EPG) {
        int e = b * EPG + tid;
        s_gs[tid] = src[e];
        s_ld[tid] = dst[e] - b * NPG;
    }
    for (int p = tid; p < EPG * NHEAD; p += 256)
        s_w[p] = w[(size_t)b * EPG * NHEAD + p];
    for (int p = tid; p < NPG * 128; p += 256) acc[p] = 0.f;
    __syncthreads();

    const int dim = c * 128 + l * 2;
    for (int le4 = 0; le4 < EPG; le4 += 4) {
        const int le = le4 + grp;
        const bf16* p = fs + (size_t)s_gs[le] * NH + dim;
        float sum0 = 0.f, sum1 = 0.f;
#pragma unroll
        for (int h = 0; h < NHEAD; ++h) {
            s16x2 v = *(const s16x2*)(p + h * HDIM);
            float wv = s_w[le * NHEAD + h];
            sum0 += wv * b2f(v[0]);
            sum1 += wv * b2f(v[1]);
        }
        float* ap = &acc[s_ld[le] * 128 + l * 2];
        atomicAdd(ap, sum0);
        atomicAdd(ap + 1, sum1);
    }
    __syncthreads();
    for (int p = tid; p < NPG * 128; p += 256) {
        int n = p >> 7, d = p & 127;
        hout[((size_t)b * NPG + n) * HDIM + c * 128 + d] =
            __float2bfloat16(acc[p]);
    }
}

// ---------------------------------------------------------------------------
// t=2: aggregate only the virtual node: hv[b,:] = sum_i sum_h wv * fs.
// grid (6, BMOL).
// ---------------------------------------------------------------------------
__global__ __launch_bounds__(256) void aggregate_virt_kernel(
    const bf16* __restrict__ fs, const float* __restrict__ wv,
    bf16* __restrict__ hv) {
    __shared__ float acc[128];
    __shared__ float s_w[48 * NHEAD];
    const int tid = threadIdx.x;
    const int c = blockIdx.x;
    const int b = blockIdx.y;
    const int grp = tid >> 6;
    const int l = tid & 63;
    for (int p = tid; p < 48 * NHEAD; p += 256)
        s_w[p] = wv[(size_t)b * 48 * NHEAD + p];
    if (tid < 128) acc[tid] = 0.f;
    __syncthreads();

    const int dim = c * 128 + l * 2;
    float sum0 = 0.f, sum1 = 0.f;
    for (int le = grp; le < 48; le += 4) {
        const bf16* p = fs + (size_t)(b * NPG + le) * NH + dim;
#pragma unroll
        for (int h = 0; h < NHEAD; ++h) {
            s16x2 v = *(const s16x2*)(p + h * HDIM);
            float w_ = s_w[le * NHEAD + h];
            sum0 += w_ * b2f(v[0]);
            sum1 += w_ * b2f(v[1]);
        }
    }
    atomicAdd(&acc[l * 2], sum0);
    atomicAdd(&acc[l * 2 + 1], sum1);
    __syncthreads();
    if (tid < 128)
        hv[(size_t)b * HDIM + c * 128 + tid] = __float2bfloat16(acc[tid]);
}

__global__ void init_memb_kernel(const float* __restrict__ mf,
                                 float* __restrict__ m32,
                                 bf16* __restrict__ m16) {
    int idx = blockIdx.x * 256 + threadIdx.x;
    float f = mf[idx];
    m32[idx] = f;
    m16[idx] = __float2bfloat16(f);
}

// GRU gates (r,z,n) + relu
__global__ void gru_gate_kernel(const float* __restrict__ gi,
                                const float* __restrict__ gh,
                                float* __restrict__ m32, bf16* __restrict__ m16,
                                float* __restrict__ outp, int last) {
    int idx = blockIdx.x * 256 + threadIdx.x;  // < BMOL*HDIM
    int b = idx / HDIM, d = idx - b * HDIM;
    const float* gib = gi + (size_t)b * G3;
    const float* ghb = gh + (size_t)b * G3;
    float ir = gib[d], iz = gib[HDIM + d], in_ = gib[2 * HDIM + d];
    float hr = ghb[d], hz = ghb[HDIM + d], hn = ghb[2 * HDIM + d];
    float r = 1.f / (1.f + __expf(-(ir + hr)));
    float z = 1.f / (1.f + __expf(-(iz + hz)));
    float n = tanhf(in_ + r * hn);
    float hprev = m32[idx];
    float hnew = (1.f - z) * n + z * hprev;
    hnew = fmaxf(hnew, 0.f);  // relu
    m32[idx] = hnew;
    m16[idx] = __float2bfloat16(hnew);
    if (last) outp[idx] = hnew;
}

// ---------------------------------------------------------------------------
extern "C" void kernel_launch(void* const* d_in, const int* in_sizes, int n_in,
                              void* d_out, int out_size, void* d_ws,
                              size_t ws_size, hipStream_t stream) {
    const float* h_nodes = (const float*)d_in[0];
    const float* mol_feat = (const float*)d_in[1];
    const float* W_src = (const float*)d_in[2];
    const float* b_src = (const float*)d_in[3];
    const float* W_dst = (const float*)d_in[4];
    const float* b_dst = (const float*)d_in[5];
    const float* attn_a = (const float*)d_in[6];
    const float* W_ih = (const float*)d_in[7];
    const float* W_hh = (const float*)d_in[8];
    const float* b_ih = (const float*)d_in[9];
    const float* b_hh = (const float*)d_in[10];
    const int* src = (const int*)d_in[11];
    const int* dst = (const int*)d_in[12];
    const int* vnids = (const int*)d_in[13];
    float* out = (float*)d_out;

    char* p = (char*)d_ws;
    auto alloc = [&](size_t bytes) {
        char* r = p;
        p += (bytes + 255) & ~(size_t)255;
        return r;
    };
    bf16* wsrcT = (bf16*)alloc((size_t)3 * NH * HDIM * 2);
    bf16* wdstT = (bf16*)alloc((size_t)3 * NH * HDIM * 2);
    bf16* wihB = (bf16*)alloc((size_t)3 * G3 * HDIM * 2);
    bf16* whhB = (bf16*)alloc((size_t)3 * G3 * HDIM * 2);
    bf16* fs = (bf16*)alloc((size_t)NNODE * NH * 2);
    bf16* fd = (bf16*)alloc((size_t)NNODE * NH * 2);
    bf16* h_ws = (bf16*)alloc((size_t)NNODE * HDIM * 2);
    float* lg = (float*)alloc((size_t)NEDGE * NHEAD * 4);
    float* w_e = (float*)alloc((size_t)NEDGE * NHEAD * 4);
    float* memb32 = (float*)alloc((size_t)BMOL * HDIM * 4);
    bf16* memb16 = (bf16*)alloc((size_t)BMOL * HDIM * 2);
    float* gi = (float*)alloc((size_t)BMOL * G3 * 4);
    float* gh = (float*)alloc((size_t)BMOL * G3 * 4);

    dim3 tgrid(NH / 64, HDIM / 64, 3);
    transpose_w<<<tgrid, 256, 0, stream>>>(W_src, wsrcT, HDIM, NH);
    transpose_w<<<tgrid, 256, 0, stream>>>(W_dst, wdstT, HDIM, NH);
    {
        int n = 3 * G3 * HDIM;
        cvt_kernel<<<(n + 255) / 256, 256, 0, stream>>>(W_ih, wihB, n);
        cvt_kernel<<<(n + 255) / 256, 256, 0, stream>>>(W_hh, whhB, n);
    }
    {
        int n = NNODE * HDIM;
        cvt_kernel<<<(n + 255) / 256, 256, 0, stream>>>(h_nodes, h_ws, n);
    }
    init_memb_kernel<<<BMOL * HDIM / 256, 256, 0, stream>>>(mol_feat, memb32,
                                                            memb16);

    for (int t = 0; t < 3; ++t) {
        if (t < 2) {
            gemm_bt8<<<dim3(24, 25, 2), 512, 0, stream>>>(
                h_ws, wsrcT + (size_t)t * NH * HDIM,
                wdstT + (size_t)t * NH * HDIM, b_src + (size_t)t * NH,
                b_dst + (size_t)t * NH, fs, fd);
            logits_kernel<<<NEDGE / 4, 256, 0, stream>>>(
                fs, fd, attn_a + (size_t)t * NHEAD * HDIM, src, dst, lg);
            softmax_kernel<<<BMOL, 256, 0, stream>>>(
                lg, dst, w_e, out + BMOL * HDIM + t * BMOL * 48);
            aggregate_kernel<<<dim3(6, BMOL), 256, 0, stream>>>(fs, w_e, src,
                                                                dst, h_ws);
            gemm_small<<<dim3(G3 / 256, 4, 2), 256, 0, stream>>>(
                h_ws, vnids, memb16, wihB + (size_t)t * G3 * HDIM,
                whhB + (size_t)t * G3 * HDIM, b_ih + (size_t)t * G3,
                b_hh + (size_t)t * G3, gi, gh, (const bf16*)nullptr);
            gru_gate_kernel<<<BMOL * HDIM / 256, 256, 0, stream>>>(
                gi, gh, memb32, memb16, out, 0);
        } else {
            // t=2: only h[virtual] and virtual-edge attns are consumed.
            // fs full (z=1 plane only); fd only for the 128 virtual rows.
            gemm_bt8<<<dim3(24, 25, 1), 512, 0, stream>>>(
                h_ws, wsrcT + (size_t)t * NH * HDIM,
                wdstT + (size_t)t * NH * HDIM, b_src + (size_t)t * NH,
                b_dst + (size_t)t * NH, fs, fd);
            gemm_gather_bt<<<dim3(NH / 256, 4), 256, 0, stream>>>(
                h_ws, vnids, wdstT + (size_t)t * NH * HDIM,
                b_dst + (size_t)t * NH, fd);  // fd[0..127] = fd_virt
            logits_virt_kernel<<<(BMOL * 48) / 4, 256, 0, stream>>>(
                fs, fd, attn_a + (size_t)t * NHEAD * HDIM, lg);
            softmax_virt_kernel<<<BMOL, 64, 0, stream>>>(
                lg, w_e, out + BMOL * HDIM + t * BMOL * 48);
            aggregate_virt_kernel<<<dim3(6, BMOL), 256, 0, stream>>>(
                fs, w_e, h_ws);  // h_ws[0..BMOL*HDIM) = h[virtual]
            gemm_small<<<dim3(G3 / 256, 4, 2), 256, 0, stream>>>(
                h_ws, vnids, memb16, wihB + (size_t)t * G3 * HDIM,
                whhB + (size_t)t * G3 * HDIM, b_ih + (size_t)t * G3,
                b_hh + (size_t)t * G3, gi, gh, h_ws);
            gru_gate_kernel<<<BMOL * HDIM / 256, 256, 0, stream>>>(
                gi, gh, memb32, memb16, out, 1);
        }
    }
}